// Round 8
// baseline (115.553 us; speedup 1.0000x reference)
//
#include <hip/hip_runtime.h>

// A: inv[b][h][w] = 1/||p[b,:,h,w]||          (ws[0 .. 256K floats))
// B: sim[b][h][w] = (1/9)*sum_c q*box3x3(q)   (ws[256K .. 512K)), q = p*inv
//    staged via global_load_lds (async, no VGPR cost) with pre-swizzled source,
//    double-buffered; edges via shuffles; issue-next-then-compute pipeline.
// C: out[b, c&1, h, w, c>>1] = p[b,c,h,w] * sim[b,h,w] via rotation-tile transpose.

typedef __attribute__((address_space(3))) unsigned int lds_uint;
typedef __attribute__((address_space(1))) const unsigned int glb_uint;

__device__ __forceinline__ void gload16(const float* g, float* l) {
    __builtin_amdgcn_global_load_lds((glb_uint*)g, (lds_uint*)l, 16, 0, 0);
}

__global__ __launch_bounds__(256) void bcim_norm(const float* __restrict__ p,
                                                 float* __restrict__ inv) {
    __shared__ float scratch[8 * 4 * 32];
    const int tid = threadIdx.x;
    const int b  = blockIdx.x >> 3;
    const int r0 = (blockIdx.x & 7) << 2;
    const float* __restrict__ pb = p + (size_t)b * 131072;
    const int csub = tid >> 5, r = (tid >> 3) & 3, wq = tid & 7;
    float4 n = make_float4(0.f, 0.f, 0.f, 0.f);
    #pragma unroll
    for (int i = 0; i < 16; ++i) {
        const int c = csub * 16 + i;
        const float4 v = *(const float4*)(pb + c * 1024 + (r0 + r) * 32 + wq * 4);
        n.x = fmaf(v.x, v.x, n.x); n.y = fmaf(v.y, v.y, n.y);
        n.z = fmaf(v.z, v.z, n.z); n.w = fmaf(v.w, v.w, n.w);
    }
    *(float4*)&scratch[csub * 128 + r * 32 + wq * 4] = n;
    __syncthreads();
    if (tid < 128) {
        const int rr = tid >> 5, w = tid & 31;
        float s = 0.f;
        #pragma unroll
        for (int k = 0; k < 8; ++k) s += scratch[k * 128 + rr * 32 + w];
        inv[b * 1024 + (rr + r0) * 32 + w] = (s > 0.f) ? (1.0f / sqrtf(s)) : 0.f;
    }
}

__global__ __launch_bounds__(256) void bcim_sim(const float* __restrict__ p,
                                                const float* __restrict__ inv,
                                                float* __restrict__ sim) {
    __shared__ float buf[2][6144];   // [row 0..5][c32 0..31][physquad 0..7][4f]
    __shared__ float invL[192];      // rows r0-1..r0+4, 0 for OOB

    const int tid = threadIdx.x;
    const int b  = blockIdx.x >> 3;
    const int r0 = (blockIdx.x & 7) << 2;
    const float* __restrict__ pb = p + (size_t)b * 131072;

    const int c32 = tid >> 3;
    const int wq  = tid & 7;
    const int wv  = tid >> 6;                 // wave id (uniform)
    const int lane = tid & 63;
    const int c_rel = lane >> 3;              // staging channel within wave's 8
    const int wq_g  = (lane & 7) ^ c_rel;     // pre-swizzled global quad
    const int sC    = wq ^ (c32 & 7);         // physical quad for logical wq

    int rg6[6];
    #pragma unroll
    for (int r = 0; r < 6; ++r) rg6[r] = min(max(r0 - 1 + r, 0), 31);

    const int stage_ch = 8 * wv + c_rel;

    #define ISSUE(cidx, bi)                                                          \
        _Pragma("unroll")                                                            \
        for (int r = 0; r < 6; ++r)                                                  \
            gload16(pb + ((cidx) * 32 + stage_ch) * 1024 + rg6[r] * 32 + wq_g * 4,   \
                    &buf[bi][r * 1024 + wv * 256]);

    ISSUE(0, 0);
    if (tid < 192) {
        const int j = tid >> 5, w = tid & 31;
        const int rg = r0 - 1 + j;
        invL[j * 32 + w] = ((unsigned)rg < 32u) ? inv[b * 1024 + rg * 32 + w] : 0.f;
    }
    __syncthreads();   // drains chunk-0 staging + invL

    const float mL = (wq > 0) ? 1.f : 0.f;
    const float mR = (wq < 7) ? 1.f : 0.f;
    float4 acc[4];
    #pragma unroll
    for (int h = 0; h < 4; ++h) acc[h] = make_float4(0.f, 0.f, 0.f, 0.f);

    #define COMPUTE(bi) {                                                            \
        float vs[6][4]; float4 ctr4[4];                                              \
        _Pragma("unroll")                                                            \
        for (int r = 0; r < 6; ++r) {                                                \
            const float4 IV = *(const float4*)&invL[r * 32 + wq * 4];                \
            const float4 P = *(const float4*)&buf[bi][(r * 32 + c32) * 32 + sC * 4]; \
            float4 q;                                                                \
            q.x = P.x * IV.x; q.y = P.y * IV.y;                                      \
            q.z = P.z * IV.z; q.w = P.w * IV.w;                                      \
            const float ql = __shfl_up(q.w, 1) * mL;                                 \
            const float qr = __shfl_down(q.x, 1) * mR;                               \
            vs[r][0] = ql  + q.x + q.y;                                              \
            vs[r][1] = q.x + q.y + q.z;                                              \
            vs[r][2] = q.y + q.z + q.w;                                              \
            vs[r][3] = q.z + q.w + qr;                                               \
            if (r >= 1 && r <= 4) ctr4[r - 1] = q;                                   \
        }                                                                            \
        _Pragma("unroll")                                                            \
        for (int h = 0; h < 4; ++h) {                                                \
            acc[h].x = fmaf(ctr4[h].x, vs[h][0] + vs[h+1][0] + vs[h+2][0], acc[h].x);\
            acc[h].y = fmaf(ctr4[h].y, vs[h][1] + vs[h+1][1] + vs[h+2][1], acc[h].y);\
            acc[h].z = fmaf(ctr4[h].z, vs[h][2] + vs[h+1][2] + vs[h+2][2], acc[h].z);\
            acc[h].w = fmaf(ctr4[h].w, vs[h][3] + vs[h+1][3] + vs[h+2][3], acc[h].w);\
        } }

    ISSUE(1, 1); COMPUTE(0); __syncthreads();
    ISSUE(2, 0); COMPUTE(1); __syncthreads();
    ISSUE(3, 1); COMPUTE(0); __syncthreads();
                 COMPUTE(1); __syncthreads();
    #undef ISSUE
    #undef COMPUTE

    // channel reduction (reuse buf[0] as R[32][4][8]*4, quad-swizzled)
    float* R = &buf[0][0];
    #pragma unroll
    for (int h = 0; h < 4; ++h)
        *(float4*)&R[(c32 * 32 + h * 8 + sC) * 4] = acc[h];
    __syncthreads();
    if (tid < 128) {
        const int h = tid >> 5, w = tid & 31;
        float s = 0.f;
        #pragma unroll
        for (int c = 0; c < 32; ++c)
            s += R[(c * 32 + h * 8 + ((w >> 2) ^ (c & 7))) * 4 + (w & 3)];
        sim[b * 1024 + (r0 + h) * 32 + w] = s * (1.0f / 9.0f);
    }
}

__global__ __launch_bounds__(256) void bcim_out(const float* __restrict__ p,
                                                const float* __restrict__ sim,
                                                float* __restrict__ out) {
    __shared__ float T[4224];
    __shared__ float simv[128];
    const int tid = threadIdx.x;
    const int b  = blockIdx.x >> 3;
    const int r0 = (blockIdx.x & 7) << 2;
    const float* __restrict__ pb = p + (size_t)b * 131072;

    if (tid < 128) simv[tid] = sim[b * 1024 + r0 * 32 + tid];

    const int wq3 = tid & 7, r3 = (tid >> 3) & 3, clb = tid >> 5;
    const int p3g = clb * 1024 + (r0 + r3) * 32 + wq3 * 4;

    float4 qa[4], qb[4];
    #pragma unroll
    for (int j = 0; j < 4; ++j) qa[j] = *(const float4*)(pb + p3g + j * 8192);
    #pragma unroll
    for (int j = 0; j < 4; ++j) qb[j] = *(const float4*)(pb + 32768 + p3g + j * 8192);
    __syncthreads();

    #define CB_BODY(cb, Q) {                                                         \
        _Pragma("unroll")                                                            \
        for (int j = 0; j < 4; ++j) {                                                \
            const int cl = j * 8 + clb;                                              \
            const int cpp = (((cl & 1) << 4) + (cl >> 1) + 9 * r3) & 31;             \
            const int basew = (r3 * 32 + wq3 * 4) * 33 + cpp;                        \
            T[basew] = Q[j].x; T[basew + 33] = Q[j].y;                               \
            T[basew + 66] = Q[j].z; T[basew + 99] = Q[j].w;                          \
        }                                                                            \
        __syncthreads();                                                             \
        if ((cb) < 2) {                                                              \
            _Pragma("unroll")                                                        \
            for (int j = 0; j < 4; ++j)                                              \
                Q[j] = *(const float4*)(pb + ((cb) + 2) * 32768 + p3g + j * 8192);   \
        }                                                                            \
        const int qb4 = (cb) << 4;                                                   \
        _Pragma("unroll")                                                            \
        for (int stp = 0; stp < 4; ++stp) {                                          \
            const int flat = stp * 256 + tid;                                        \
            const int qf = flat & 3;                                                 \
            const int t  = (flat >> 2) & 1;                                          \
            const int pp = flat >> 3;                                                \
            const int hh = pp >> 5;                                                  \
            const int ww = pp & 31;                                                  \
            const float sm = simv[pp];                                               \
            const int cb2 = t * 16 + qf * 4 + 9 * hh;                                \
            const int ai  = pp * 33;                                                 \
            float4 o;                                                                \
            o.x = T[ai + ((cb2 + 0) & 31)] * sm;                                     \
            o.y = T[ai + ((cb2 + 1) & 31)] * sm;                                     \
            o.z = T[ai + ((cb2 + 2) & 31)] * sm;                                     \
            o.w = T[ai + ((cb2 + 3) & 31)] * sm;                                     \
            *(float4*)(out + (size_t)b * 131072 + (size_t)t * 65536 +                \
                       (size_t)(r0 + hh) * 2048 + ww * 64 + qb4 + qf * 4) = o;       \
        }                                                                            \
        __syncthreads(); }

    CB_BODY(0, qa)
    CB_BODY(1, qb)
    CB_BODY(2, qa)
    CB_BODY(3, qb)
    #undef CB_BODY
}

extern "C" void kernel_launch(void* const* d_in, const int* in_sizes, int n_in,
                              void* d_out, int out_size, void* d_ws, size_t ws_size,
                              hipStream_t stream) {
    const float* p = (const float*)d_in[0];
    float* out = (float*)d_out;
    float* inv = (float*)d_ws;            // 1 MB
    float* sim = inv + 262144;            // 1 MB
    bcim_norm<<<dim3(2048), dim3(256), 0, stream>>>(p, inv);
    bcim_sim <<<dim3(2048), dim3(256), 0, stream>>>(p, inv, sim);
    bcim_out <<<dim3(2048), dim3(256), 0, stream>>>(p, sim, out);
    (void)in_sizes; (void)n_in; (void)out_size; (void)ws_size;
}

// Round 9
// 93.332 us; speedup vs baseline: 1.2381x; 1.2381x over previous
//
#include <hip/hip_runtime.h>

// K1 (bcim_sim): reads p ONCE. Per (b, 4-row strip): stream 16 chunks of 8
//   channels through an XOR-swizzled LDS slab (v3-verified), accumulate 9
//   per-position sums S_d = sum_c p[x]*p[x+d]; inv = 1/sqrt(S_center);
//   sim = (1/9)*inv*sum_d inv[x+d]*S_d  ->  ws (1 MB). 2-deep reg prefetch.
// K2 (bcim_out): out[b, c&1, h, w, c>>1] = p[b,c,h,w] * sim[b,h,w] via the
//   v8-verified [128][33] rotation-tile transpose (reads p once, writes out).

__device__ __forceinline__ float dot4acc(float4 a, float4 b, float acc) {
    acc = fmaf(a.x, b.x, acc);
    acc = fmaf(a.y, b.y, acc);
    acc = fmaf(a.z, b.z, acc);
    acc = fmaf(a.w, b.w, acc);
    return acc;
}

__global__ __launch_bounds__(256) void bcim_sim(const float* __restrict__ p,
                                                float* __restrict__ sim) {
    __shared__ float slab[1536];   // [6 rows][64 quads][4]
    __shared__ float invL[192];

    const int tid = threadIdx.x;
    const int b  = blockIdx.x >> 3;
    const int r0 = (blockIdx.x & 7) << 2;
    const float* __restrict__ pb = p + (size_t)b * 131072;

    // loader mapping (v3-verified)
    const int l_wq = tid & 7;
    const int l_c  = (tid >> 3) & 7;
    const int l_r  = tid >> 6;
    const int g0r  = r0 - 1 + l_r;
    const int g1r  = r0 + 3 + l_r;
    const bool in0 = ((unsigned)g0r < 32u);
    const bool in1 = (tid < 128) && ((unsigned)g1r < 32u);
    int wOff[4];
    {
        const int ch = l_c >> 2;
        const int ci = l_c & 3;
        #pragma unroll
        for (int j = 0; j < 4; ++j) {
            const int u = ((l_wq << 3) + (j << 1) + ch) ^ l_wq;
            wOff[j] = l_r * 256 + u * 4 + ci;
        }
    }
    const int gOff0 = l_c * 1024 + g0r * 32 + l_wq * 4;
    const int gOff1 = l_c * 1024 + g1r * 32 + l_wq * 4;

    // stencil mapping (v3-verified)
    const int chalf = tid & 1;
    const int pos   = tid >> 1;
    const int h     = pos >> 5;
    const int w     = pos & 31;
    const int wm    = (w > 0) ? w - 1 : 0;
    const int wp    = (w < 31) ? w + 1 : 31;
    const int uc    = (w  * 2 + chalf) ^ (w  >> 2);
    const int um    = (wm * 2 + chalf) ^ (wm >> 2);
    const int up    = (wp * 2 + chalf) ^ (wp >> 2);

    // 2-deep prefetch buffers (A = even chunks, B = odd chunks)
    float4 A0 = make_float4(0.f,0.f,0.f,0.f), A1 = A0, B0 = A0, B1 = A0;
    if (in0) A0 = *(const float4*)(pb + gOff0);
    if (in1) A1 = *(const float4*)(pb + gOff1);
    if (in0) B0 = *(const float4*)(pb + 8192 + gOff0);
    if (in1) B1 = *(const float4*)(pb + 8192 + gOff1);

    float s0=0.f,s1=0.f,s2=0.f,s3=0.f,s4=0.f,s5=0.f,s6=0.f,s7=0.f,s8=0.f,hn=0.f;

    #define STEP(R0, R1, NEXTC) {                                                   \
        slab[wOff[0]] = R0.x; slab[wOff[1]] = R0.y;                                 \
        slab[wOff[2]] = R0.z; slab[wOff[3]] = R0.w;                                 \
        if (tid < 128) {                                                            \
            slab[wOff[0] + 1024] = R1.x; slab[wOff[1] + 1024] = R1.y;               \
            slab[wOff[2] + 1024] = R1.z; slab[wOff[3] + 1024] = R1.w;               \
        }                                                                           \
        __syncthreads();                                                            \
        if ((NEXTC) < 16) {                                                         \
            if (in0) R0 = *(const float4*)(pb + (NEXTC) * 8192 + gOff0);            \
            if (in1) R1 = *(const float4*)(pb + (NEXTC) * 8192 + gOff1);            \
        }                                                                           \
        {                                                                           \
            const float4* sp = (const float4*)slab;                                 \
            const float4 ctr = sp[(h + 1) * 64 + uc];                               \
            float4 n0 = sp[h * 64 + um];                                            \
            float4 n1 = sp[h * 64 + uc];                                            \
            float4 n2 = sp[h * 64 + up];                                            \
            s0 = dot4acc(ctr, n0, s0);                                              \
            s1 = dot4acc(ctr, n1, s1);                                              \
            s2 = dot4acc(ctr, n2, s2);                                              \
            if (h == 0) hn = dot4acc(n1, n1, hn);                                   \
            n0 = sp[(h + 2) * 64 + um];                                             \
            n1 = sp[(h + 2) * 64 + uc];                                             \
            n2 = sp[(h + 2) * 64 + up];                                             \
            s6 = dot4acc(ctr, n0, s6);                                              \
            s7 = dot4acc(ctr, n1, s7);                                              \
            s8 = dot4acc(ctr, n2, s8);                                              \
            if (h == 3) hn = dot4acc(n1, n1, hn);                                   \
            n0 = sp[(h + 1) * 64 + um];                                             \
            n2 = sp[(h + 1) * 64 + up];                                             \
            s3 = dot4acc(ctr, n0, s3);                                              \
            s4 = dot4acc(ctr, ctr, s4);                                             \
            s5 = dot4acc(ctr, n2, s5);                                              \
        }                                                                           \
        __syncthreads(); }

    #pragma unroll
    for (int ch = 0; ch < 16; ch += 2) {
        STEP(A0, A1, ch + 2)
        STEP(B0, B1, ch + 3)
    }
    #undef STEP

    // pair-reduce channel halves (lanes 2k <-> 2k+1)
    s0 += __shfl_xor(s0, 1); s1 += __shfl_xor(s1, 1); s2 += __shfl_xor(s2, 1);
    s3 += __shfl_xor(s3, 1); s4 += __shfl_xor(s4, 1); s5 += __shfl_xor(s5, 1);
    s6 += __shfl_xor(s6, 1); s7 += __shfl_xor(s7, 1); s8 += __shfl_xor(s8, 1);
    hn += __shfl_xor(hn, 1);

    // inv-norms + sim (v3-verified)
    if (chalf == 0) {
        invL[(h + 1) * 32 + w] = (s4 > 0.f) ? (1.0f / sqrtf(s4)) : 0.f;
        if (h == 0) invL[w]       = (hn > 0.f) ? (1.0f / sqrtf(hn)) : 0.f;
        if (h == 3) invL[160 + w] = (hn > 0.f) ? (1.0f / sqrtf(hn)) : 0.f;
    }
    __syncthreads();
    if (chalf == 0) {
        const float mL = (w > 0)  ? 1.f : 0.f;
        const float mR = (w < 31) ? 1.f : 0.f;
        const float* iT = invL + h * 32;
        const float* iM = iT + 32;
        const float* iB = iM + 32;
        float acc;
        acc = s0 * (iT[wm] * mL);
        acc = fmaf(s1, iT[w],       acc);
        acc = fmaf(s2, iT[wp] * mR, acc);
        acc = fmaf(s3, iM[wm] * mL, acc);
        acc = fmaf(s4, iM[w],       acc);
        acc = fmaf(s5, iM[wp] * mR, acc);
        acc = fmaf(s6, iB[wm] * mL, acc);
        acc = fmaf(s7, iB[w],       acc);
        acc = fmaf(s8, iB[wp] * mR, acc);
        sim[b * 1024 + (r0 + h) * 32 + w] = acc * iM[w] * (1.0f / 9.0f);
    }
}

__global__ __launch_bounds__(256) void bcim_out(const float* __restrict__ p,
                                                const float* __restrict__ sim,
                                                float* __restrict__ out) {
    __shared__ float T[4224];
    __shared__ float simv[128];
    const int tid = threadIdx.x;
    const int b  = blockIdx.x >> 3;
    const int r0 = (blockIdx.x & 7) << 2;
    const float* __restrict__ pb = p + (size_t)b * 131072;

    if (tid < 128) simv[tid] = sim[b * 1024 + r0 * 32 + tid];

    const int wq3 = tid & 7, r3 = (tid >> 3) & 3, clb = tid >> 5;
    const int p3g = clb * 1024 + (r0 + r3) * 32 + wq3 * 4;

    float4 qa[4], qb[4];
    #pragma unroll
    for (int j = 0; j < 4; ++j) qa[j] = *(const float4*)(pb + p3g + j * 8192);
    #pragma unroll
    for (int j = 0; j < 4; ++j) qb[j] = *(const float4*)(pb + 32768 + p3g + j * 8192);
    __syncthreads();

    #define CB_BODY(cb, Q) {                                                         \
        _Pragma("unroll")                                                            \
        for (int j = 0; j < 4; ++j) {                                                \
            const int cl = j * 8 + clb;                                              \
            const int cpp = (((cl & 1) << 4) + (cl >> 1) + 9 * r3) & 31;             \
            const int basew = (r3 * 32 + wq3 * 4) * 33 + cpp;                        \
            T[basew] = Q[j].x; T[basew + 33] = Q[j].y;                               \
            T[basew + 66] = Q[j].z; T[basew + 99] = Q[j].w;                          \
        }                                                                            \
        __syncthreads();                                                             \
        if ((cb) < 2) {                                                              \
            _Pragma("unroll")                                                        \
            for (int j = 0; j < 4; ++j)                                              \
                Q[j] = *(const float4*)(pb + ((cb) + 2) * 32768 + p3g + j * 8192);   \
        }                                                                            \
        const int qb4 = (cb) << 4;                                                   \
        _Pragma("unroll")                                                            \
        for (int stp = 0; stp < 4; ++stp) {                                          \
            const int flat = stp * 256 + tid;                                        \
            const int qf = flat & 3;                                                 \
            const int t  = (flat >> 2) & 1;                                          \
            const int pp = flat >> 3;                                                \
            const int hh = pp >> 5;                                                  \
            const int ww = pp & 31;                                                  \
            const float sm = simv[pp];                                               \
            const int cb2 = t * 16 + qf * 4 + 9 * hh;                                \
            const int ai  = pp * 33;                                                 \
            float4 o;                                                                \
            o.x = T[ai + ((cb2 + 0) & 31)] * sm;                                     \
            o.y = T[ai + ((cb2 + 1) & 31)] * sm;                                     \
            o.z = T[ai + ((cb2 + 2) & 31)] * sm;                                     \
            o.w = T[ai + ((cb2 + 3) & 31)] * sm;                                     \
            *(float4*)(out + (size_t)b * 131072 + (size_t)t * 65536 +                \
                       (size_t)(r0 + hh) * 2048 + ww * 64 + qb4 + qf * 4) = o;       \
        }                                                                            \
        __syncthreads(); }

    CB_BODY(0, qa)
    CB_BODY(1, qb)
    CB_BODY(2, qa)
    CB_BODY(3, qb)
    #undef CB_BODY
}

extern "C" void kernel_launch(void* const* d_in, const int* in_sizes, int n_in,
                              void* d_out, int out_size, void* d_ws, size_t ws_size,
                              hipStream_t stream) {
    const float* p = (const float*)d_in[0];
    float* out = (float*)d_out;
    float* sim = (float*)d_ws;            // 1 MB
    bcim_sim<<<dim3(2048), dim3(256), 0, stream>>>(p, sim);
    bcim_out<<<dim3(2048), dim3(256), 0, stream>>>(p, sim, out);
    (void)in_sizes; (void)n_in; (void)out_size; (void)ws_size;
}

// Round 10
// 60.220 us; speedup vs baseline: 1.9188x; 1.5498x over previous
//
#include <hip/hip_runtime.h>

// Fused, reads p ONCE. Per (b, 4-row strip):
//  phase 1: stream 16 chunks of 8 channels through XOR-swizzled slab (v3-verified),
//           accumulate 9 sums S_d = sum_c p[x]*p[x+d]; RETAIN each chunk's center
//           quad in keep[16] (lane (pos,chalf) ends holding p[c,pos] for its 64 ch).
//  phase 2: inv = 1/sqrt(S_center) (+halo norms), sim = (1/9)*inv*sum_d inv[x+d]*S_d,
//           computed redundantly in both chalf lanes (pair-reduce gives both full sums).
//  phase 3: out[b, c&1, h, w, c>>1] = keep * sim via [128][36] tile, 4 b128
//           conflict-free writes + 16 scalar reads per thread per 32-ch block.
//           ZERO global re-reads.

__device__ __forceinline__ float dot4acc(float4 a, float4 b, float acc) {
    acc = fmaf(a.x, b.x, acc);
    acc = fmaf(a.y, b.y, acc);
    acc = fmaf(a.z, b.z, acc);
    acc = fmaf(a.w, b.w, acc);
    return acc;
}

__global__ __launch_bounds__(256) void bcim_fused(const float* __restrict__ p,
                                                  float* __restrict__ out) {
    __shared__ float shbuf[4608];   // phase1: slab [6][64 quads][4] (1536 f); phase3: T[128][36]
    __shared__ float invL[192];

    const int tid = threadIdx.x;
    const int b  = blockIdx.x >> 3;
    const int r0 = (blockIdx.x & 7) << 2;
    const float* __restrict__ pb = p + (size_t)b * 131072;
    float* slab = shbuf;

    // ---- loader mapping (v3-verified) ----
    const int l_wq = tid & 7;
    const int l_c  = (tid >> 3) & 7;
    const int l_r  = tid >> 6;
    const int g0r  = r0 - 1 + l_r;
    const int g1r  = r0 + 3 + l_r;
    const bool in0 = ((unsigned)g0r < 32u);
    const bool in1 = (tid < 128) && ((unsigned)g1r < 32u);
    int wOff[4];
    {
        const int chh = l_c >> 2;
        const int ci  = l_c & 3;
        #pragma unroll
        for (int j = 0; j < 4; ++j) {
            const int u = ((l_wq << 3) + (j << 1) + chh) ^ l_wq;
            wOff[j] = l_r * 256 + u * 4 + ci;
        }
    }
    const int gOff0 = l_c * 1024 + g0r * 32 + l_wq * 4;
    const int gOff1 = l_c * 1024 + g1r * 32 + l_wq * 4;

    // ---- stencil mapping (v3-verified) ----
    const int chalf = tid & 1;
    const int pos   = tid >> 1;
    const int h     = pos >> 5;
    const int w     = pos & 31;
    const int wm    = (w > 0) ? w - 1 : 0;
    const int wp    = (w < 31) ? w + 1 : 31;
    const int uc    = (w  * 2 + chalf) ^ (w  >> 2);
    const int um    = (wm * 2 + chalf) ^ (wm >> 2);
    const int up    = (wp * 2 + chalf) ^ (wp >> 2);

    // 2-deep prefetch (A = even chunks, B = odd chunks)
    float4 A0 = make_float4(0.f,0.f,0.f,0.f), A1 = A0, B0 = A0, B1 = A0;
    if (in0) A0 = *(const float4*)(pb + gOff0);
    if (in1) A1 = *(const float4*)(pb + gOff1);
    if (in0) B0 = *(const float4*)(pb + 8192 + gOff0);
    if (in1) B1 = *(const float4*)(pb + 8192 + gOff1);

    float s0=0.f,s1=0.f,s2=0.f,s3=0.f,s4=0.f,s5=0.f,s6=0.f,s7=0.f,s8=0.f,hn=0.f;
    float4 keep[16];

    #define STEP(R0, R1, NEXTC, CUR) {                                              \
        slab[wOff[0]] = R0.x; slab[wOff[1]] = R0.y;                                 \
        slab[wOff[2]] = R0.z; slab[wOff[3]] = R0.w;                                 \
        if (tid < 128) {                                                            \
            slab[wOff[0] + 1024] = R1.x; slab[wOff[1] + 1024] = R1.y;               \
            slab[wOff[2] + 1024] = R1.z; slab[wOff[3] + 1024] = R1.w;               \
        }                                                                           \
        __syncthreads();                                                            \
        if ((NEXTC) < 16) {                                                         \
            if (in0) R0 = *(const float4*)(pb + (NEXTC) * 8192 + gOff0);            \
            if (in1) R1 = *(const float4*)(pb + (NEXTC) * 8192 + gOff1);            \
        }                                                                           \
        {                                                                           \
            const float4* sp = (const float4*)slab;                                 \
            const float4 ctr = sp[(h + 1) * 64 + uc];                               \
            keep[CUR] = ctr;                                                        \
            float4 n0 = sp[h * 64 + um];                                            \
            float4 n1 = sp[h * 64 + uc];                                            \
            float4 n2 = sp[h * 64 + up];                                            \
            s0 = dot4acc(ctr, n0, s0);                                              \
            s1 = dot4acc(ctr, n1, s1);                                              \
            s2 = dot4acc(ctr, n2, s2);                                              \
            if (h == 0) hn = dot4acc(n1, n1, hn);                                   \
            n0 = sp[(h + 2) * 64 + um];                                             \
            n1 = sp[(h + 2) * 64 + uc];                                             \
            n2 = sp[(h + 2) * 64 + up];                                             \
            s6 = dot4acc(ctr, n0, s6);                                              \
            s7 = dot4acc(ctr, n1, s7);                                              \
            s8 = dot4acc(ctr, n2, s8);                                              \
            if (h == 3) hn = dot4acc(n1, n1, hn);                                   \
            n0 = sp[(h + 1) * 64 + um];                                             \
            n2 = sp[(h + 1) * 64 + up];                                             \
            s3 = dot4acc(ctr, n0, s3);                                              \
            s4 = dot4acc(ctr, ctr, s4);                                             \
            s5 = dot4acc(ctr, n2, s5);                                              \
        }                                                                           \
        __syncthreads(); }

    #pragma unroll
    for (int ch = 0; ch < 16; ch += 2) {
        STEP(A0, A1, ch + 2, ch)
        STEP(B0, B1, ch + 3, ch + 1)
    }
    #undef STEP

    // pair-reduce channel halves (lanes 2k <-> 2k+1): both lanes get full sums
    s0 += __shfl_xor(s0, 1); s1 += __shfl_xor(s1, 1); s2 += __shfl_xor(s2, 1);
    s3 += __shfl_xor(s3, 1); s4 += __shfl_xor(s4, 1); s5 += __shfl_xor(s5, 1);
    s6 += __shfl_xor(s6, 1); s7 += __shfl_xor(s7, 1); s8 += __shfl_xor(s8, 1);
    hn += __shfl_xor(hn, 1);

    // inv-norms (chalf==0 writes; values identical in both lanes)
    if (chalf == 0) {
        invL[(h + 1) * 32 + w] = (s4 > 0.f) ? (1.0f / sqrtf(s4)) : 0.f;
        if (h == 0) invL[w]       = (hn > 0.f) ? (1.0f / sqrtf(hn)) : 0.f;
        if (h == 3) invL[160 + w] = (hn > 0.f) ? (1.0f / sqrtf(hn)) : 0.f;
    }
    __syncthreads();

    // sim — computed in BOTH chalf lanes
    float simreg;
    {
        const float mL = (w > 0)  ? 1.f : 0.f;
        const float mR = (w < 31) ? 1.f : 0.f;
        const float* iT = invL + h * 32;
        const float* iM = iT + 32;
        const float* iB = iM + 32;
        float acc;
        acc = s0 * (iT[wm] * mL);
        acc = fmaf(s1, iT[w],       acc);
        acc = fmaf(s2, iT[wp] * mR, acc);
        acc = fmaf(s3, iM[wm] * mL, acc);
        acc = fmaf(s4, iM[w],       acc);
        acc = fmaf(s5, iM[wp] * mR, acc);
        acc = fmaf(s6, iB[wm] * mL, acc);
        acc = fmaf(s7, iB[w],       acc);
        acc = fmaf(s8, iB[wp] * mR, acc);
        simreg = acc * iM[w] * (1.0f / 9.0f);
    }
    __syncthreads();   // all waves done with slab/invL before tile overwrite

    // ---- phase 3: output from registers via T[128][36] tile ----
    float* T = shbuf;
    #pragma unroll
    for (int cb = 0; cb < 4; ++cb) {
        #pragma unroll
        for (int m = 0; m < 4; ++m) {
            float4 v = keep[cb * 4 + m];
            v.x *= simreg; v.y *= simreg; v.z *= simreg; v.w *= simreg;
            *(float4*)&T[pos * 36 + m * 8 + chalf * 4] = v;
        }
        __syncthreads();
        #pragma unroll
        for (int stp = 0; stp < 4; ++stp) {
            const int flat = stp * 256 + tid;
            const int qf = flat & 3;
            const int t  = (flat >> 2) & 1;
            const int pp = flat >> 3;
            const int hh = pp >> 5;
            const int ww = pp & 31;
            const int cbase = pp * 36 + qf * 8 + t;
            float4 o;
            o.x = T[cbase + 0];
            o.y = T[cbase + 2];
            o.z = T[cbase + 4];
            o.w = T[cbase + 6];
            *(float4*)(out + (size_t)b * 131072 + (size_t)t * 65536 +
                       (size_t)(r0 + hh) * 2048 + ww * 64 + cb * 16 + qf * 4) = o;
        }
        __syncthreads();
    }
}

extern "C" void kernel_launch(void* const* d_in, const int* in_sizes, int n_in,
                              void* d_out, int out_size, void* d_ws, size_t ws_size,
                              hipStream_t stream) {
    const float* p = (const float*)d_in[0];
    float* out = (float*)d_out;
    bcim_fused<<<dim3(2048), dim3(256), 0, stream>>>(p, out);
    (void)in_sizes; (void)n_in; (void)out_size; (void)d_ws; (void)ws_size;
}